// Round 5
// baseline (271.300 us; speedup 1.0000x reference)
//
#include <hip/hip_runtime.h>

// StandGCN2: 2-layer GCN, N=100000, E=600000, 128->128(relu)->64, bf16 I/O.
// R5: mega-fusion. Layer1+Layer2-GEMM in one kernel using (AX)W1 and (h1)W2:
//   per-wave: gather-aggregate AX for 16 nodes -> LDS -> MFMA W1t -> relu+b1
//   -> LDS round-trip -> MFMA W2t -> g = h1*W2 [N,64]. Then agg2 gathers g (+b2).
// Eliminates h/h1/h2 intermediates (~100 MB traffic) and 2 dispatches.

typedef unsigned short u16;
typedef unsigned int u32;
typedef __attribute__((ext_vector_type(8))) short bf16x8;
typedef __attribute__((ext_vector_type(4))) float f32x4;

__device__ __forceinline__ float b2f(u16 s) {
  return __uint_as_float(((u32)s) << 16);
}
__device__ __forceinline__ u16 f2b(float f) {
  u32 u = __float_as_uint(f);
  u32 r = (u + 0x7FFFu + ((u >> 16) & 1u)) >> 16;
  return (u16)r;
}
__device__ __forceinline__ u32 pk2(float a, float b) {
  return (u32)f2b(a) | ((u32)f2b(b) << 16);
}
__device__ __forceinline__ void dec8(uint4 v, float f[8]) {
  f[0] = __uint_as_float(v.x << 16);
  f[1] = __uint_as_float(v.x & 0xFFFF0000u);
  f[2] = __uint_as_float(v.y << 16);
  f[3] = __uint_as_float(v.y & 0xFFFF0000u);
  f[4] = __uint_as_float(v.z << 16);
  f[5] = __uint_as_float(v.z & 0xFFFF0000u);
  f[6] = __uint_as_float(v.w << 16);
  f[7] = __uint_as_float(v.w & 0xFFFF0000u);
}
__device__ __forceinline__ void fma8(uint4 v, float d, float acc[8]) {
  acc[0] = fmaf(__uint_as_float(v.x << 16), d, acc[0]);
  acc[1] = fmaf(__uint_as_float(v.x & 0xFFFF0000u), d, acc[1]);
  acc[2] = fmaf(__uint_as_float(v.y << 16), d, acc[2]);
  acc[3] = fmaf(__uint_as_float(v.y & 0xFFFF0000u), d, acc[3]);
  acc[4] = fmaf(__uint_as_float(v.z << 16), d, acc[4]);
  acc[5] = fmaf(__uint_as_float(v.z & 0xFFFF0000u), d, acc[5]);
  acc[6] = fmaf(__uint_as_float(v.w << 16), d, acc[6]);
  acc[7] = fmaf(__uint_as_float(v.w & 0xFFFF0000u), d, acc[7]);
}
// 8 features of row `row` from x (bf16 or fp32 per mcv), feature offset l16*8
__device__ __forceinline__ void load8x(const void* xraw, int row, int l16, int mcv,
                                       float f[8]) {
  if (mcv) {
    const float* xp = (const float*)xraw + (size_t)row * 128 + l16 * 8;
    float4 a = *(const float4*)xp;
    float4 b = *(const float4*)(xp + 4);
    f[0] = a.x; f[1] = a.y; f[2] = a.z; f[3] = a.w;
    f[4] = b.x; f[5] = b.y; f[6] = b.z; f[7] = b.w;
  } else {
    uint4 v = *(const uint4*)((const u16*)xraw + (size_t)row * 128 + l16 * 8);
    dec8(v, f);
  }
}

// ---------------- probe dtype + zero cnt (fused) ----------------

__global__ __launch_bounds__(256) void zero_probe_k(const u16* __restrict__ w,
                                                    int* __restrict__ mode,
                                                    int* __restrict__ cnt, int np,
                                                    int nu16) {
  int i = blockIdx.x * 256 + threadIdx.x;
  if (i < np) cnt[i] = 0;
  if (blockIdx.x == 0) {
    __shared__ int cnt_s;
    if (threadIdx.x == 0) cnt_s = 0;
    __syncthreads();
    int c = 0;
    for (int j = threadIdx.x; j < nu16; j += 256) {
      u32 e = (w[j] >> 7) & 0xFFu;
      if (e >= 100u && e <= 130u) c++;
    }
    atomicAdd(&cnt_s, c);
    __syncthreads();
    if (threadIdx.x == 0) *mode = (cnt_s < (nu16 * 13) / 16) ? 1 : 0;  // 1 = fp32
  }
}

// weights -> bf16, TRANSPOSED: W1t[n*128+k] (n<128), W2t[n*128+k] (n<64); biases flat
__global__ __launch_bounds__(256) void cvtw_k(const void* W1, const void* b1,
                                              const void* W2, const void* b2,
                                              u16* __restrict__ W1t, u16* __restrict__ ob1,
                                              u16* __restrict__ W2t, u16* __restrict__ ob2,
                                              const int* __restrict__ mode) {
  int m = *mode;
  int i = blockIdx.x * 256 + threadIdx.x;
  int j = i;
  const void* src;
  u16* dst;
  int sidx, didx;
  if (j < 16384) {
    int n = j >> 7, k = j & 127;
    src = W1; dst = W1t; sidx = k * 128 + n; didx = j;
  } else if ((j -= 16384) < 128) {
    src = b1; dst = ob1; sidx = j; didx = j;
  } else if ((j -= 128) < 8192) {
    int n = j >> 7, k = j & 127;
    src = W2; dst = W2t; sidx = k * 64 + n; didx = j;
  } else if ((j -= 8192) < 64) {
    src = b2; dst = ob2; sidx = j; didx = j;
  } else
    return;
  dst[didx] = m ? f2b(((const float*)src)[sidx]) : ((const u16*)src)[sidx];
}

// ---------------- CSR build ----------------

__global__ __launch_bounds__(256) void count_k(const int* __restrict__ dst,
                                               int* __restrict__ cnt, int E) {
  int e = blockIdx.x * 256 + threadIdx.x;
  if (e < E) atomicAdd(&cnt[dst[e]], 1);
}

__global__ __launch_bounds__(256) void scan1(const int* __restrict__ cnt,
                                             int* __restrict__ offs,
                                             int* __restrict__ bsum, int np) {
  __shared__ int lds[256];
  int t = threadIdx.x;
  int i = blockIdx.x * 256 + t;
  int v = cnt[i];
  lds[t] = v;
  __syncthreads();
#pragma unroll
  for (int off = 1; off < 256; off <<= 1) {
    int add = (t >= off) ? lds[t - off] : 0;
    __syncthreads();
    lds[t] += add;
    __syncthreads();
  }
  offs[i] = lds[t] - v;
  if (t == 0) bsum[blockIdx.x] = lds[255];
}

__global__ __launch_bounds__(512) void scan2(const int* __restrict__ bsum,
                                             int* __restrict__ bscan, int nb) {
  __shared__ int lds[512];
  int t = threadIdx.x;
  int v = (t < nb) ? bsum[t] : 0;
  lds[t] = v;
  __syncthreads();
#pragma unroll
  for (int off = 1; off < 512; off <<= 1) {
    int add = (t >= off) ? lds[t - off] : 0;
    __syncthreads();
    lds[t] += add;
    __syncthreads();
  }
  bscan[t] = lds[t] - v;
}

__global__ __launch_bounds__(256) void scan3(const int* __restrict__ offs,
                                             const int* __restrict__ bscan,
                                             int* __restrict__ cursor,
                                             const int* __restrict__ cnt,
                                             float* __restrict__ dinv,
                                             int4* __restrict__ ninfo, int np) {
  int i = blockIdx.x * 256 + threadIdx.x;
  int o = offs[i] + bscan[blockIdx.x];
  cursor[i] = o;
  int c = cnt[i];
  float dv = rsqrtf((float)c + 1.0f);  // +1 self-loop
  dinv[i] = dv;
  ninfo[i] = make_int4(o, c, __float_as_int(dv), 0);
}

__global__ __launch_bounds__(256) void fill_k(const int* __restrict__ src,
                                              const int* __restrict__ dst,
                                              int* __restrict__ cursor,
                                              const float* __restrict__ dinv,
                                              int2* __restrict__ sp, int E) {
  int e = blockIdx.x * 256 + threadIdx.x;
  if (e < E) {
    int s = src[e];
    float ds = dinv[s];
    int p = atomicAdd(&cursor[dst[e]], 1);
    sp[p] = make_int2(s, __float_as_int(ds));
  }
}

// ---------------- fused layer1 + layer2-GEMM ----------------
// Block = 128 threads (2 waves), each wave self-contained: 16 nodes.
// Phase A: quarter-wave gather-aggregate (AX)*di -> bf16 -> own LDS As tile.
// Phase B: MFMA As x W1t (B-frags from global, L1-resident), relu+b1 -> Hs.
// Phase C: MFMA Hs x W2t -> g[N,64]. No __syncthreads (per-wave LDS regions,
// DS ops within a wave are in-order).
// Layouts (m89/m91): A[m=lane&15][k=(lane>>4)*8+j]; C/D col=lane&15, row=(lane>>4)*4+reg.

__global__ __launch_bounds__(128) void fused1(const void* __restrict__ xraw,
                                              const int2* __restrict__ sp,
                                              const int4* __restrict__ ninfo,
                                              const u16* __restrict__ W1t,
                                              const u16* __restrict__ b1,
                                              const u16* __restrict__ W2t,
                                              u16* __restrict__ g, int n,
                                              const int* __restrict__ mode) {
  __shared__ __align__(16) u16 As[2][16 * 136];
  __shared__ __align__(16) u16 Hs[2][16 * 136];
  const int tid = threadIdx.x, wv = tid >> 6, lane = tid & 63;
  const int lq = lane >> 4, lr = lane & 15;  // quarter, lane-in-quarter
  const int mcv = *mode;
  const int base = (blockIdx.x * 2 + wv) * 16;

  // ---- Phase A: 4 rounds x 4 nodes ----
  for (int r4 = 0; r4 < 4; ++r4) {
    const int i = base + r4 * 4 + lq;
    const bool valid = (i < n);
    int start = 0, c = 0;
    float di = 0.f;
    if (valid) {
      int4 ni = ninfo[i];
      start = ni.x;
      c = ni.y;
      di = __int_as_float(ni.z);
    }
    float acc[8];
    {
      float f[8] = {0.f, 0.f, 0.f, 0.f, 0.f, 0.f, 0.f, 0.f};
      if (valid) load8x(xraw, i, lr, mcv, f);
#pragma unroll
      for (int j = 0; j < 8; ++j) acc[j] = f[j] * di;
    }
    const int bl = lq * 16;
    for (int bs = 0; __any(bs < c); bs += 16) {
      int m = c - bs;
      m = m < 0 ? 0 : (m > 16 ? 16 : m);
      int s = 0, db = 0;
      if (lr < m) {
        int2 p = sp[start + bs + lr];
        s = p.x;
        db = p.y;
      }
      int mmw = m;
      mmw = max(mmw, __shfl_xor(mmw, 16));
      mmw = max(mmw, __shfl_xor(mmw, 32));
      for (int e = 0; e < mmw; e += 2) {
        int s0 = __shfl(s, bl + e);
        int s1 = __shfl(s, bl + e + 1);
        float d0 = __int_as_float(__shfl(db, bl + e));
        float d1 = __int_as_float(__shfl(db, bl + e + 1));
        float f0[8], f1[8];
        load8x(xraw, s0, lr, mcv, f0);
        load8x(xraw, s1, lr, mcv, f1);
#pragma unroll
        for (int j = 0; j < 8; ++j)
          acc[j] = fmaf(f0[j], d0, fmaf(f1[j], d1, acc[j]));
      }
    }
    uint4 ov;
    ov.x = pk2(acc[0] * di, acc[1] * di);
    ov.y = pk2(acc[2] * di, acc[3] * di);
    ov.z = pk2(acc[4] * di, acc[5] * di);
    ov.w = pk2(acc[6] * di, acc[7] * di);
    *(uint4*)&As[wv][(r4 * 4 + lq) * 136 + lr * 8] = ov;
  }

  // ---- Phase B: (AX) x W1 -> relu+b1 -> Hs ----
  bf16x8 a[4];
#pragma unroll
  for (int s = 0; s < 4; ++s)
    a[s] = *(const bf16x8*)&As[wv][lr * 136 + s * 32 + lq * 8];

#pragma unroll
  for (int nt = 0; nt < 8; ++nt) {
    f32x4 acc4 = {0.f, 0.f, 0.f, 0.f};
#pragma unroll
    for (int s = 0; s < 4; ++s) {
      bf16x8 b = *(const bf16x8*)&W1t[(nt * 16 + lr) * 128 + s * 32 + lq * 8];
      acc4 = __builtin_amdgcn_mfma_f32_16x16x32_bf16(a[s], b, acc4, 0, 0, 0);
    }
    float bb = b2f(b1[nt * 16 + lr]);
#pragma unroll
    for (int r = 0; r < 4; ++r) {
      float o = fmaxf(acc4[r] + bb, 0.f);
      Hs[wv][(lq * 4 + r) * 136 + nt * 16 + lr] = f2b(o);
    }
  }

  // ---- Phase C: h1 x W2 -> g ----
  bf16x8 a2[4];
#pragma unroll
  for (int s = 0; s < 4; ++s)
    a2[s] = *(const bf16x8*)&Hs[wv][lr * 136 + s * 32 + lq * 8];

#pragma unroll
  for (int nt = 0; nt < 4; ++nt) {
    f32x4 acc4 = {0.f, 0.f, 0.f, 0.f};
#pragma unroll
    for (int s = 0; s < 4; ++s) {
      bf16x8 b = *(const bf16x8*)&W2t[(nt * 16 + lr) * 128 + s * 32 + lq * 8];
      acc4 = __builtin_amdgcn_mfma_f32_16x16x32_bf16(a2[s], b, acc4, 0, 0, 0);
    }
#pragma unroll
    for (int r = 0; r < 4; ++r) {
      int row = base + lq * 4 + r;
      if (row < n) g[(size_t)row * 64 + nt * 16 + lr] = f2b(acc4[r]);
    }
  }
}

// ---------------- agg2: oct-wave over g, 8 nodes/wave ----------------

__global__ __launch_bounds__(256) void agg2(const u16* __restrict__ g,
                                            const int2* __restrict__ sp,
                                            const int4* __restrict__ ninfo,
                                            const u16* __restrict__ b2,
                                            void* __restrict__ outv, int n,
                                            const int* __restrict__ mode) {
  const int lane = threadIdx.x & 63;
  const int o8 = lane >> 3, l8 = lane & 7;
  const int i = blockIdx.x * 32 + (threadIdx.x >> 6) * 8 + o8;
  const bool valid = (i < n);

  int start = 0, c = 0;
  float di = 0.f;
  if (valid) {
    int4 ni = ninfo[i];
    start = ni.x;
    c = ni.y;
    di = __int_as_float(ni.z);
  }

  float acc[8];
  {
    uint4 v = valid ? *(const uint4*)(g + (size_t)i * 64 + l8 * 8)
                    : make_uint4(0u, 0u, 0u, 0u);
    float f[8];
    dec8(v, f);
#pragma unroll
    for (int j = 0; j < 8; ++j) acc[j] = f[j] * di;
  }

  const int bl = o8 * 8;
  for (int base = 0; __any(base < c); base += 8) {
    int m = c - base;
    m = m < 0 ? 0 : (m > 8 ? 8 : m);
    int s = 0, db = 0;
    if (l8 < m) {
      int2 p = sp[start + base + l8];
      s = p.x;
      db = p.y;
    }
    int mmw = m;
    mmw = max(mmw, __shfl_xor(mmw, 8));
    mmw = max(mmw, __shfl_xor(mmw, 16));
    mmw = max(mmw, __shfl_xor(mmw, 32));
    for (int e = 0; e < mmw; e += 2) {
      int s0 = __shfl(s, bl + e);
      int s1 = __shfl(s, bl + e + 1);
      float d0 = __int_as_float(__shfl(db, bl + e));
      float d1 = __int_as_float(__shfl(db, bl + e + 1));
      uint4 v0 = *(const uint4*)(g + (size_t)s0 * 64 + l8 * 8);
      uint4 v1 = *(const uint4*)(g + (size_t)s1 * 64 + l8 * 8);
      fma8(v0, d0, acc);
      fma8(v1, d1, acc);
    }
  }

  if (valid) {
    uint4 bv = *(const uint4*)(b2 + l8 * 8);
    float bf[8];
    dec8(bv, bf);
    float o[8];
#pragma unroll
    for (int j = 0; j < 8; ++j) o[j] = fmaf(acc[j], di, bf[j]);
    if (*mode) {
      float* op = (float*)outv + (size_t)i * 64 + l8 * 8;
      *(float4*)op = make_float4(o[0], o[1], o[2], o[3]);
      *(float4*)(op + 4) = make_float4(o[4], o[5], o[6], o[7]);
    } else {
      uint4 ov;
      ov.x = pk2(o[0], o[1]);
      ov.y = pk2(o[2], o[3]);
      ov.z = pk2(o[4], o[5]);
      ov.w = pk2(o[6], o[7]);
      *(uint4*)((u16*)outv + (size_t)i * 64 + l8 * 8) = ov;
    }
  }
}

// ---------------- launch ----------------

extern "C" void kernel_launch(void* const* d_in, const int* in_sizes, int n_in,
                              void* d_out, int out_size, void* d_ws, size_t ws_size,
                              hipStream_t stream) {
  const void* x_raw  = d_in[0];
  const int*  ei     = (const int*)d_in[1];
  const void* W1_raw = d_in[2];
  const void* b1_raw = d_in[3];
  const void* W2_raw = d_in[4];
  const void* b2_raw = d_in[5];

  const int N = in_sizes[0] / 128;
  const int E = in_sizes[1] / 2;
  const int* srcA = ei;
  const int* dstA = ei + E;

  const int NP = ((N + 255) / 256) * 256;
  const int NB = NP / 256;

  char* ws = (char*)d_ws;
  size_t off = 0;
  auto alloc = [&](size_t bytes) -> void* {
    void* p = ws + off;
    off = (off + bytes + 255) & ~(size_t)255;
    return p;
  };
  int*   mode   = (int*)alloc(4);
  int*   cnt    = (int*)alloc((size_t)NP * 4);
  float* dinv   = (float*)alloc((size_t)NP * 4);
  int*   offs   = (int*)alloc((size_t)NP * 4);
  int*   cursor = (int*)alloc((size_t)NP * 4);
  int*   bsum   = (int*)alloc(512 * 4);
  int*   bscan  = (int*)alloc(512 * 4);
  int4*  ninfo  = (int4*)alloc((size_t)NP * 16);
  int2*  sp     = (int2*)alloc((size_t)E * 8);
  u16*   W1t    = (u16*)alloc((size_t)128 * 128 * 2);
  u16*   b1b    = (u16*)alloc(128 * 2);
  u16*   W2t    = (u16*)alloc((size_t)64 * 128 * 2);
  u16*   b2b    = (u16*)alloc(64 * 2);
  u16*   g      = (u16*)alloc((size_t)N * 64 * 2);

  zero_probe_k<<<NB, 256, 0, stream>>>((const u16*)W1_raw, mode, cnt, NP, in_sizes[2]);
  cvtw_k<<<(24768 + 255) / 256, 256, 0, stream>>>(W1_raw, b1_raw, W2_raw, b2_raw,
                                                  W1t, b1b, W2t, b2b, mode);

  const int eb = (E + 255) / 256;
  count_k<<<eb, 256, 0, stream>>>(dstA, cnt, E);
  scan1<<<NB, 256, 0, stream>>>(cnt, offs, bsum, NP);
  scan2<<<1, 512, 0, stream>>>(bsum, bscan, NB);
  scan3<<<NB, 256, 0, stream>>>(offs, bscan, cursor, cnt, dinv, ninfo, NP);
  fill_k<<<eb, 256, 0, stream>>>(srcA, dstA, cursor, dinv, sp, E);

  fused1<<<(N + 31) / 32, 128, 0, stream>>>(x_raw, sp, ninfo, W1t, b1b, W2t, g, N, mode);
  agg2<<<(N + 31) / 32, 256, 0, stream>>>(g, sp, ninfo, b2b, d_out, N, mode);
}

// Round 6
// 250.070 us; speedup vs baseline: 1.0849x; 1.0849x over previous
//
#include <hip/hip_runtime.h>

// StandGCN2: 2-layer GCN, N=100000, E=600000, 128->128(relu)->64, bf16 I/O.
// R6: fusion with R4-parallelism. fusedA: block=256 (4 waves, 16 nodes), each
// wave gathers Ax for 4 nodes (quarter-wave, ONE round, unroll-4) -> shared
// 16x128 LDS tile -> 4 waves cooperatively MFMA W1(+relu+b1) -> LDS -> MFMA W2
// -> g[N,64]. agg2 gathers g (+b2) -> out. No h/h1/h2 intermediates.

typedef unsigned short u16;
typedef unsigned int u32;
typedef __attribute__((ext_vector_type(8))) short bf16x8;
typedef __attribute__((ext_vector_type(4))) float f32x4;

__device__ __forceinline__ float b2f(u16 s) {
  return __uint_as_float(((u32)s) << 16);
}
__device__ __forceinline__ u16 f2b(float f) {
  u32 u = __float_as_uint(f);
  u32 r = (u + 0x7FFFu + ((u >> 16) & 1u)) >> 16;
  return (u16)r;
}
__device__ __forceinline__ u32 pk2(float a, float b) {
  return (u32)f2b(a) | ((u32)f2b(b) << 16);
}
__device__ __forceinline__ void dec8(uint4 v, float f[8]) {
  f[0] = __uint_as_float(v.x << 16);
  f[1] = __uint_as_float(v.x & 0xFFFF0000u);
  f[2] = __uint_as_float(v.y << 16);
  f[3] = __uint_as_float(v.y & 0xFFFF0000u);
  f[4] = __uint_as_float(v.z << 16);
  f[5] = __uint_as_float(v.z & 0xFFFF0000u);
  f[6] = __uint_as_float(v.w << 16);
  f[7] = __uint_as_float(v.w & 0xFFFF0000u);
}
__device__ __forceinline__ void fma8(uint4 v, float d, float acc[8]) {
  acc[0] = fmaf(__uint_as_float(v.x << 16), d, acc[0]);
  acc[1] = fmaf(__uint_as_float(v.x & 0xFFFF0000u), d, acc[1]);
  acc[2] = fmaf(__uint_as_float(v.y << 16), d, acc[2]);
  acc[3] = fmaf(__uint_as_float(v.y & 0xFFFF0000u), d, acc[3]);
  acc[4] = fmaf(__uint_as_float(v.z << 16), d, acc[4]);
  acc[5] = fmaf(__uint_as_float(v.z & 0xFFFF0000u), d, acc[5]);
  acc[6] = fmaf(__uint_as_float(v.w << 16), d, acc[6]);
  acc[7] = fmaf(__uint_as_float(v.w & 0xFFFF0000u), d, acc[7]);
}
__device__ __forceinline__ void load8x(const void* xraw, int row, int l16, int mcv,
                                       float f[8]) {
  if (mcv) {
    const float* xp = (const float*)xraw + (size_t)row * 128 + l16 * 8;
    float4 a = *(const float4*)xp;
    float4 b = *(const float4*)(xp + 4);
    f[0] = a.x; f[1] = a.y; f[2] = a.z; f[3] = a.w;
    f[4] = b.x; f[5] = b.y; f[6] = b.z; f[7] = b.w;
  } else {
    uint4 v = *(const uint4*)((const u16*)xraw + (size_t)row * 128 + l16 * 8);
    dec8(v, f);
  }
}

// ---------------- probe dtype + zero cnt (fused) ----------------

__global__ __launch_bounds__(256) void zero_probe_k(const u16* __restrict__ w,
                                                    int* __restrict__ mode,
                                                    int* __restrict__ cnt, int np,
                                                    int nu16) {
  int i = blockIdx.x * 256 + threadIdx.x;
  if (i < np) cnt[i] = 0;
  if (blockIdx.x == 0) {
    __shared__ int cnt_s;
    if (threadIdx.x == 0) cnt_s = 0;
    __syncthreads();
    int c = 0;
    for (int j = threadIdx.x; j < nu16; j += 256) {
      u32 e = (w[j] >> 7) & 0xFFu;
      if (e >= 100u && e <= 130u) c++;
    }
    atomicAdd(&cnt_s, c);
    __syncthreads();
    if (threadIdx.x == 0) *mode = (cnt_s < (nu16 * 13) / 16) ? 1 : 0;  // 1 = fp32
  }
}

// weights -> bf16 TRANSPOSED: W1t[n*128+k] (n<128), W2t[n*128+k] (n<64); biases flat
__global__ __launch_bounds__(256) void cvtw_k(const void* W1, const void* b1,
                                              const void* W2, const void* b2,
                                              u16* __restrict__ W1t, u16* __restrict__ ob1,
                                              u16* __restrict__ W2t, u16* __restrict__ ob2,
                                              const int* __restrict__ mode) {
  int m = *mode;
  int i = blockIdx.x * 256 + threadIdx.x;
  int j = i;
  const void* src;
  u16* dst;
  int sidx, didx;
  if (j < 16384) {
    int n = j >> 7, k = j & 127;
    src = W1; dst = W1t; sidx = k * 128 + n; didx = j;
  } else if ((j -= 16384) < 128) {
    src = b1; dst = ob1; sidx = j; didx = j;
  } else if ((j -= 128) < 8192) {
    int n = j >> 7, k = j & 127;
    src = W2; dst = W2t; sidx = k * 64 + n; didx = j;
  } else if ((j -= 8192) < 64) {
    src = b2; dst = ob2; sidx = j; didx = j;
  } else
    return;
  dst[didx] = m ? f2b(((const float*)src)[sidx]) : ((const u16*)src)[sidx];
}

// ---------------- CSR build ----------------

__global__ __launch_bounds__(256) void count_k(const int* __restrict__ dst,
                                               int* __restrict__ cnt, int E) {
  int e = blockIdx.x * 256 + threadIdx.x;
  if (e < E) atomicAdd(&cnt[dst[e]], 1);
}

__global__ __launch_bounds__(256) void scan1(const int* __restrict__ cnt,
                                             int* __restrict__ offs,
                                             int* __restrict__ bsum, int np) {
  __shared__ int lds[256];
  int t = threadIdx.x;
  int i = blockIdx.x * 256 + t;
  int v = cnt[i];
  lds[t] = v;
  __syncthreads();
#pragma unroll
  for (int off = 1; off < 256; off <<= 1) {
    int add = (t >= off) ? lds[t - off] : 0;
    __syncthreads();
    lds[t] += add;
    __syncthreads();
  }
  offs[i] = lds[t] - v;
  if (t == 0) bsum[blockIdx.x] = lds[255];
}

__global__ __launch_bounds__(512) void scan2(const int* __restrict__ bsum,
                                             int* __restrict__ bscan, int nb) {
  __shared__ int lds[512];
  int t = threadIdx.x;
  int v = (t < nb) ? bsum[t] : 0;
  lds[t] = v;
  __syncthreads();
#pragma unroll
  for (int off = 1; off < 512; off <<= 1) {
    int add = (t >= off) ? lds[t - off] : 0;
    __syncthreads();
    lds[t] += add;
    __syncthreads();
  }
  bscan[t] = lds[t] - v;
}

__global__ __launch_bounds__(256) void scan3(const int* __restrict__ offs,
                                             const int* __restrict__ bscan,
                                             int* __restrict__ cursor,
                                             const int* __restrict__ cnt,
                                             float* __restrict__ dinv,
                                             int4* __restrict__ ninfo, int np) {
  int i = blockIdx.x * 256 + threadIdx.x;
  int o = offs[i] + bscan[blockIdx.x];
  cursor[i] = o;
  int c = cnt[i];
  float dv = rsqrtf((float)c + 1.0f);  // +1 self-loop
  dinv[i] = dv;
  ninfo[i] = make_int4(o, c, __float_as_int(dv), 0);
}

__global__ __launch_bounds__(256) void fill_k(const int* __restrict__ src,
                                              const int* __restrict__ dst,
                                              int* __restrict__ cursor,
                                              const float* __restrict__ dinv,
                                              int2* __restrict__ sp, int E) {
  int e = blockIdx.x * 256 + threadIdx.x;
  if (e < E) {
    int s = src[e];
    float ds = dinv[s];
    int p = atomicAdd(&cursor[dst[e]], 1);
    sp[p] = make_int2(s, __float_as_int(ds));
  }
}

// ---------------- fusedA: gather Ax (R4-style parallelism) + W1,relu,b1 + W2 ----------------
// Block 256 = 4 waves = 16 nodes; wave wv handles nodes base+wv*4+lq (ONE gather
// round per wave, unroll-4). Shared As 16x128 tile -> wave wv MFMAs W1 cols
// [32wv,32wv+32) -> Hs -> wave wv MFMAs W2 cols [16wv,16wv+16) -> g.
// Layouts (m89/m91, R5-verified): A[m=lane&15][k=(lane>>4)*8+j];
// C/D col=lane&15, row=(lane>>4)*4+reg.

__global__ __launch_bounds__(256) void fusedA(const void* __restrict__ xraw,
                                              const int2* __restrict__ sp,
                                              const int4* __restrict__ ninfo,
                                              const u16* __restrict__ W1t,
                                              const u16* __restrict__ b1,
                                              const u16* __restrict__ W2t,
                                              u16* __restrict__ g, int n,
                                              const int* __restrict__ mode) {
  __shared__ __align__(16) u16 As[16 * 136];
  __shared__ __align__(16) u16 Hs[16 * 136];
  const int tid = threadIdx.x, wv = tid >> 6, lane = tid & 63;
  const int lq = lane >> 4, lr = lane & 15;
  const int mcv = *mode;
  const int base = blockIdx.x * 16;
  const int i = base + wv * 4 + lq;
  const bool valid = (i < n);

  // ---- gather phase (one round per wave, 4 nodes via quarters) ----
  int start = 0, c = 0;
  float di = 0.f;
  if (valid) {
    int4 ni = ninfo[i];
    start = ni.x;
    c = ni.y;
    di = __int_as_float(ni.z);
  }
  float acc[8];
  {
    float f[8] = {0.f, 0.f, 0.f, 0.f, 0.f, 0.f, 0.f, 0.f};
    if (valid) load8x(xraw, i, lr, mcv, f);
#pragma unroll
    for (int j = 0; j < 8; ++j) acc[j] = f[j] * di;
  }
  const int bl = lq * 16;
  for (int bs = 0; __any(bs < c); bs += 16) {
    int m = c - bs;
    m = m < 0 ? 0 : (m > 16 ? 16 : m);
    int s = 0, db = 0;
    if (lr < m) {
      int2 p = sp[start + bs + lr];
      s = p.x;
      db = p.y;
    }
    int mmw = m;
    mmw = max(mmw, __shfl_xor(mmw, 16));
    mmw = max(mmw, __shfl_xor(mmw, 32));
    for (int e = 0; e < mmw; e += 4) {  // lanes bl+e..bl+e+3 <= bl+15: safe
      int s0 = __shfl(s, bl + e), s1 = __shfl(s, bl + e + 1);
      int s2 = __shfl(s, bl + e + 2), s3 = __shfl(s, bl + e + 3);
      float d0 = __int_as_float(__shfl(db, bl + e));
      float d1 = __int_as_float(__shfl(db, bl + e + 1));
      float d2 = __int_as_float(__shfl(db, bl + e + 2));
      float d3 = __int_as_float(__shfl(db, bl + e + 3));
      float f0[8], f1[8], f2[8], f3[8];
      load8x(xraw, s0, lr, mcv, f0);
      load8x(xraw, s1, lr, mcv, f1);
      load8x(xraw, s2, lr, mcv, f2);
      load8x(xraw, s3, lr, mcv, f3);
#pragma unroll
      for (int j = 0; j < 8; ++j)
        acc[j] = fmaf(f0[j], d0,
                 fmaf(f1[j], d1, fmaf(f2[j], d2, fmaf(f3[j], d3, acc[j]))));
    }
  }
  {
    uint4 ov;
    ov.x = pk2(acc[0] * di, acc[1] * di);
    ov.y = pk2(acc[2] * di, acc[3] * di);
    ov.z = pk2(acc[4] * di, acc[5] * di);
    ov.w = pk2(acc[6] * di, acc[7] * di);
    *(uint4*)&As[(wv * 4 + lq) * 136 + lr * 8] = ov;
  }
  __syncthreads();

  // ---- W1 MFMA: wave wv -> col tiles 2wv, 2wv+1 ----
  bf16x8 a[4];
#pragma unroll
  for (int s = 0; s < 4; ++s)
    a[s] = *(const bf16x8*)&As[lr * 136 + s * 32 + lq * 8];

#pragma unroll
  for (int t = 0; t < 2; ++t) {
    const int nt = wv * 2 + t;
    f32x4 acc4 = {0.f, 0.f, 0.f, 0.f};
#pragma unroll
    for (int s = 0; s < 4; ++s) {
      bf16x8 b = *(const bf16x8*)&W1t[(nt * 16 + lr) * 128 + s * 32 + lq * 8];
      acc4 = __builtin_amdgcn_mfma_f32_16x16x32_bf16(a[s], b, acc4, 0, 0, 0);
    }
    float bb = b2f(b1[nt * 16 + lr]);
#pragma unroll
    for (int r = 0; r < 4; ++r) {
      float o = fmaxf(acc4[r] + bb, 0.f);
      Hs[(lq * 4 + r) * 136 + nt * 16 + lr] = f2b(o);
    }
  }
  __syncthreads();

  // ---- W2 MFMA: wave wv -> col tile wv ----
  bf16x8 a2[4];
#pragma unroll
  for (int s = 0; s < 4; ++s)
    a2[s] = *(const bf16x8*)&Hs[lr * 136 + s * 32 + lq * 8];

  {
    const int nt = wv;
    f32x4 acc4 = {0.f, 0.f, 0.f, 0.f};
#pragma unroll
    for (int s = 0; s < 4; ++s) {
      bf16x8 b = *(const bf16x8*)&W2t[(nt * 16 + lr) * 128 + s * 32 + lq * 8];
      acc4 = __builtin_amdgcn_mfma_f32_16x16x32_bf16(a2[s], b, acc4, 0, 0, 0);
    }
#pragma unroll
    for (int r = 0; r < 4; ++r) {
      int row = base + lq * 4 + r;
      if (row < n) g[(size_t)row * 64 + nt * 16 + lr] = f2b(acc4[r]);
    }
  }
}

// ---------------- agg2: oct-wave over g, 8 nodes/wave, unroll-4 ----------------

__global__ __launch_bounds__(256) void agg2(const u16* __restrict__ g,
                                            const int2* __restrict__ sp,
                                            const int4* __restrict__ ninfo,
                                            const u16* __restrict__ b2,
                                            void* __restrict__ outv, int n,
                                            const int* __restrict__ mode) {
  const int lane = threadIdx.x & 63;
  const int o8 = lane >> 3, l8 = lane & 7;
  const int i = blockIdx.x * 32 + (threadIdx.x >> 6) * 8 + o8;
  const bool valid = (i < n);

  int start = 0, c = 0;
  float di = 0.f;
  if (valid) {
    int4 ni = ninfo[i];
    start = ni.x;
    c = ni.y;
    di = __int_as_float(ni.z);
  }

  float acc[8];
  {
    uint4 v = valid ? *(const uint4*)(g + (size_t)i * 64 + l8 * 8)
                    : make_uint4(0u, 0u, 0u, 0u);
    float f[8];
    dec8(v, f);
#pragma unroll
    for (int j = 0; j < 8; ++j) acc[j] = f[j] * di;
  }

  const int bl = o8 * 8;
  for (int base = 0; __any(base < c); base += 8) {
    int m = c - base;
    m = m < 0 ? 0 : (m > 8 ? 8 : m);
    int s = 0, db = 0;
    if (l8 < m) {
      int2 p = sp[start + base + l8];
      s = p.x;
      db = p.y;
    }
    int mmw = m;
    mmw = max(mmw, __shfl_xor(mmw, 8));
    mmw = max(mmw, __shfl_xor(mmw, 16));
    mmw = max(mmw, __shfl_xor(mmw, 32));
    for (int e = 0; e < mmw; e += 4) {  // lanes bl+e..bl+e+3 <= bl+7: safe
      int s0 = __shfl(s, bl + e), s1 = __shfl(s, bl + e + 1);
      int s2 = __shfl(s, bl + e + 2), s3 = __shfl(s, bl + e + 3);
      float d0 = __int_as_float(__shfl(db, bl + e));
      float d1 = __int_as_float(__shfl(db, bl + e + 1));
      float d2 = __int_as_float(__shfl(db, bl + e + 2));
      float d3 = __int_as_float(__shfl(db, bl + e + 3));
      uint4 v0 = *(const uint4*)(g + (size_t)s0 * 64 + l8 * 8);
      uint4 v1 = *(const uint4*)(g + (size_t)s1 * 64 + l8 * 8);
      uint4 v2 = *(const uint4*)(g + (size_t)s2 * 64 + l8 * 8);
      uint4 v3 = *(const uint4*)(g + (size_t)s3 * 64 + l8 * 8);
      fma8(v0, d0, acc);
      fma8(v1, d1, acc);
      fma8(v2, d2, acc);
      fma8(v3, d3, acc);
    }
  }

  if (valid) {
    uint4 bv = *(const uint4*)(b2 + l8 * 8);
    float bf[8];
    dec8(bv, bf);
    float o[8];
#pragma unroll
    for (int j = 0; j < 8; ++j) o[j] = fmaf(acc[j], di, bf[j]);
    if (*mode) {
      float* op = (float*)outv + (size_t)i * 64 + l8 * 8;
      *(float4*)op = make_float4(o[0], o[1], o[2], o[3]);
      *(float4*)(op + 4) = make_float4(o[4], o[5], o[6], o[7]);
    } else {
      uint4 ov;
      ov.x = pk2(o[0], o[1]);
      ov.y = pk2(o[2], o[3]);
      ov.z = pk2(o[4], o[5]);
      ov.w = pk2(o[6], o[7]);
      *(uint4*)((u16*)outv + (size_t)i * 64 + l8 * 8) = ov;
    }
  }
}

// ---------------- launch ----------------

extern "C" void kernel_launch(void* const* d_in, const int* in_sizes, int n_in,
                              void* d_out, int out_size, void* d_ws, size_t ws_size,
                              hipStream_t stream) {
  const void* x_raw  = d_in[0];
  const int*  ei     = (const int*)d_in[1];
  const void* W1_raw = d_in[2];
  const void* b1_raw = d_in[3];
  const void* W2_raw = d_in[4];
  const void* b2_raw = d_in[5];

  const int N = in_sizes[0] / 128;
  const int E = in_sizes[1] / 2;
  const int* srcA = ei;
  const int* dstA = ei + E;

  const int NP = ((N + 255) / 256) * 256;
  const int NB = NP / 256;

  char* ws = (char*)d_ws;
  size_t off = 0;
  auto alloc = [&](size_t bytes) -> void* {
    void* p = ws + off;
    off = (off + bytes + 255) & ~(size_t)255;
    return p;
  };
  int*   mode   = (int*)alloc(4);
  int*   cnt    = (int*)alloc((size_t)NP * 4);
  float* dinv   = (float*)alloc((size_t)NP * 4);
  int*   offs   = (int*)alloc((size_t)NP * 4);
  int*   cursor = (int*)alloc((size_t)NP * 4);
  int*   bsum   = (int*)alloc(512 * 4);
  int*   bscan  = (int*)alloc(512 * 4);
  int4*  ninfo  = (int4*)alloc((size_t)NP * 16);
  int2*  sp     = (int2*)alloc((size_t)E * 8);
  u16*   W1t    = (u16*)alloc((size_t)128 * 128 * 2);
  u16*   b1b    = (u16*)alloc(128 * 2);
  u16*   W2t    = (u16*)alloc((size_t)64 * 128 * 2);
  u16*   b2b    = (u16*)alloc(64 * 2);
  u16*   g      = (u16*)alloc((size_t)N * 64 * 2);

  zero_probe_k<<<NB, 256, 0, stream>>>((const u16*)W1_raw, mode, cnt, NP, in_sizes[2]);
  cvtw_k<<<(24768 + 255) / 256, 256, 0, stream>>>(W1_raw, b1_raw, W2_raw, b2_raw,
                                                  W1t, b1b, W2t, b2b, mode);

  const int eb = (E + 255) / 256;
  count_k<<<eb, 256, 0, stream>>>(dstA, cnt, E);
  scan1<<<NB, 256, 0, stream>>>(cnt, offs, bsum, NP);
  scan2<<<1, 512, 0, stream>>>(bsum, bscan, NB);
  scan3<<<NB, 256, 0, stream>>>(offs, bscan, cursor, cnt, dinv, NP ? ninfo : ninfo, NP);
  fill_k<<<eb, 256, 0, stream>>>(srcA, dstA, cursor, dinv, sp, E);

  fusedA<<<(N + 15) / 16, 256, 0, stream>>>(x_raw, sp, ninfo, W1t, b1b, W2t, g, N, mode);
  agg2<<<(N + 31) / 32, 256, 0, stream>>>(g, sp, ninfo, b2b, d_out, N, mode);
}